// Round 15
// baseline (139.915 us; speedup 1.0000x reference)
//
#include <hip/hip_runtime.h>
#include <math.h>

#define BH  16384   // half batch
#define B2  32768
#define DIM 256
#define KC  1024    // clusters

typedef __bf16 bf16x8 __attribute__((ext_vector_type(8)));
typedef float  f32x4  __attribute__((ext_vector_type(4)));

__device__ __forceinline__ unsigned short f2bf(float f) {
  unsigned int u = __float_as_uint(f);
  u += 0x7FFFu + ((u >> 16) & 1u);   // RNE; inputs are finite
  return (unsigned short)(u >> 16);
}

__device__ __forceinline__ float vsqrt(float x) {
  float r; asm("v_sqrt_f32 %0, %1" : "=v"(r) : "v"(x)); return r;
}

__device__ __forceinline__ void gld_lds16(const void* g, void* l) {
  __builtin_amdgcn_global_load_lds(
      (const __attribute__((address_space(1))) void*)g,
      (__attribute__((address_space(3))) void*)l, 16, 0, 0);
}

// one wave per row: l2-normalize and convert to bf16.
// Blocks 0..15 also zero colsum; block 16 zeros out.
__global__ void norm_rows_kernel(const float* __restrict__ z,
                                 const float* __restrict__ p,
                                 const float* __restrict__ c,
                                 unsigned short* __restrict__ Xn,
                                 unsigned short* __restrict__ Cn,
                                 float* __restrict__ colsum,
                                 float* __restrict__ out) {
  if (blockIdx.x < 16) colsum[blockIdx.x * 256 + threadIdx.x] = 0.0f;
  if (blockIdx.x == 16 && threadIdx.x == 0) out[0] = 0.0f;

  int wave = threadIdx.x >> 6;
  int lane = threadIdx.x & 63;
  int row  = blockIdx.x * 4 + wave;          // 0 .. 66559
  const float* src; unsigned short* dst; int r;
  if (row < B2)        { src = z; dst = Xn; r = row; }
  else if (row < 2*B2) { src = p; dst = Xn + (size_t)B2 * DIM; r = row - B2; }
  else                 { src = c; dst = Cn; r = row - 2*B2; }
  float4 v = *reinterpret_cast<const float4*>(src + (size_t)r * DIM + lane * 4);
  float ss = v.x*v.x + v.y*v.y + v.z*v.z + v.w*v.w;
  #pragma unroll
  for (int m = 1; m < 64; m <<= 1) ss += __shfl_xor(ss, m);
  float inv = 1.0f / fmaxf(vsqrt(ss), 1e-12f);
  ushort4 o;
  o.x = f2bf(v.x * inv); o.y = f2bf(v.y * inv);
  o.z = f2bf(v.z * inv); o.w = f2bf(v.w * inv);
  *reinterpret_cast<ushort4*>(dst + (size_t)r * DIM + lane * 4) = o;
}

__global__ void fin_logC_kernel(const float* __restrict__ colsum,
                                float* __restrict__ logC) {
  int i = blockIdx.x * 256 + threadIdx.x;
  if (i < 4 * KC) logC[i] = 40.0f + __logf(colsum[i]);
}

// gemm_s: S[mat][b][k] = u8 quantized dot; colsum[mat][k] += LUT[e]
// r14 base with ONE structural change: B (Cn, 0.5MB, L2-resident) is read
// DIRECTLY from global into bF fragments -- no LDS staging for B. This
// halves the LDS pipe load (16 -> 8 ds_read/t-step) and shrinks LDS to
// 36KB -> 4 blocks/CU at the same ~120 VGPR (launch_bounds(256,2) is a
// min; HW runs 4 blocks when regs+LDS allow). Byte-equivalence of direct
// chunk (kc*4+l4) vs staged-XOR path verified (involution cancels).
__global__ __launch_bounds__(256, 2)
void gemm_s_kernel(const unsigned short* __restrict__ XA,  // [4][BH][DIM]
                   const unsigned short* __restrict__ Cn,  // [KC][DIM]
                   float* __restrict__ colsum,
                   unsigned char* __restrict__ S) {        // [4][BH][KC] u8
  __shared__ __align__(16) char lds[36864];  // A: 2x16KB | LUT 4KB @32768
  float* lut4 = (float*)(lds + 32768);
  const int id  = blockIdx.x;            // 1024
  const int xcd = id & 7, idx = id >> 3;
  const int wk  = xcd * 128 + idx;       // bijective (1024 % 8 == 0)
  const int panel = wk >> 3, col = wk & 7;
  const int tm0 = panel * 128, tn0 = col * 128;

  const int tid  = threadIdx.x;
  const int lane = tid & 63;
  const int wid  = tid >> 6;
  const int wm   = wid >> 1, wn = wid & 1;
  const int l15  = lane & 15, l4 = lane >> 4;
  const int slot = tid & 3;

  int arow[4], acs[4];
  #pragma unroll
  for (int it = 0; it < 4; ++it) {
    int sl = it * 256 + tid;
    int r = sl >> 3, c = sl & 7;
    arow[it] = r;
    acs[it]  = c ^ (r & 7);    // pre-swizzled source chunk (involution)
  }
  const char* Abase = (const char*)XA + (size_t)tm0 * 512;
  const char* Bbase = (const char*)Cn + (size_t)tn0 * 512;

  // A-only staging: tile = 128 rows x 128 B = 1024 slots of 16 B
  auto stage = [&](int t) {
    const int mat = t >> 2;
    const int bk  = t & 3;
    const int b   = t & 1;
    const char* ab = Abase + ((size_t)mat << 23);   // mat * BH * 512
    #pragma unroll
    for (int it = 0; it < 4; ++it) {
      gld_lds16(ab + (size_t)arow[it] * 512 + bk * 128 + acs[it] * 16,
                lds + b * 16384 + (it * 256 + tid) * 16);
    }
  };

  // build LUT (before the barrier that precedes first compute)
  if (tid < 256) {
    float d = ((float)tid - 127.5f) * (1.0f / 255.0f);
    float L = 20.0f * vsqrt(2.0f - 2.0f * d);
    float v = __expf(L - 40.0f);
    ((float4*)lut4)[tid] = (float4){v, v, v, v};
  }

  f32x4 acc[4][4];
  stage(0);
  __syncthreads();

  for (int t = 0; t < 16; ++t) {
    if (t < 15) stage(t + 1);
    const int b  = t & 1;
    const int mat = t >> 2, bk = t & 3;

    if (bk == 0) {
      #pragma unroll
      for (int fi = 0; fi < 4; ++fi)
        #pragma unroll
        for (int fj = 0; fj < 4; ++fj)
          acc[fi][fj] = (f32x4){0.f, 0.f, 0.f, 0.f};
    }

    #pragma unroll
    for (int kc = 0; kc < 2; ++kc) {
      bf16x8 aF[4], bF[4];
      #pragma unroll
      for (int f = 0; f < 4; ++f) {
        // B fragment straight from L2-resident global (no LDS round-trip)
        const int rb = wn * 64 + f * 16 + l15;
        bF[f] = *reinterpret_cast<const bf16x8*>(
            Bbase + (size_t)rb * 512 + bk * 128 + ((kc << 2) | l4) * 16);
        const int ra = wm * 64 + f * 16 + l15;
        aF[f] = *reinterpret_cast<const bf16x8*>(
            lds + b * 16384 + ra * 128 + ((((kc << 2) | l4) ^ (ra & 7)) << 4));
      }
      #pragma unroll
      for (int fi = 0; fi < 4; ++fi)
        #pragma unroll
        for (int fj = 0; fj < 4; ++fj)
          acc[fi][fj] = __builtin_amdgcn_mfma_f32_16x16x32_bf16(
              aF[fi], bF[fj], acc[fi][fj], 0, 0, 0);
    }

    if (bk == 3) {
      unsigned char* Sp = S + ((size_t)mat * BH + tm0) * KC + tn0;
      #pragma unroll
      for (int fj = 0; fj < 4; ++fj) {
        float cp = 0.0f;
        #pragma unroll
        for (int fi = 0; fi < 4; ++fi)
          #pragma unroll
          for (int i = 0; i < 4; ++i) {
            float v = fmaf(acc[fi][fj][i], 255.0f, 128.0f);
            v = fminf(fmaxf(v, 0.0f), 255.0f);
            unsigned e = (unsigned)v;
            cp += lut4[(e << 2) | slot];
            int row  = wm * 64 + fi * 16 + l4 * 4 + i;
            int ccol = wn * 64 + fj * 16 + l15;
            Sp[(size_t)row * KC + ccol] = (unsigned char)e;
          }
        cp += __shfl_xor(cp, 16);
        cp += __shfl_xor(cp, 32);
        if (l4 == 0)
          atomicAdd(&colsum[mat * KC + tn0 + wn * 64 + fj * 16 + l15], cp);
      }
    }
    __syncthreads();
  }
}

// decode u8 -> G = L(d_e) - lc
__device__ __forceinline__ float decG(unsigned e, float lc) {
  float d = fmaf((float)e, 1.0f / 255.0f, -0.5f);
  float L = 20.0f * vsqrt(fmaf(-2.0f, d, 2.0f));
  return L - lc;
}

// one wave per row: 4 uint4 loads cover the full row in all 4 planes.
__global__ __launch_bounds__(256)
void pass2_mem_kernel(const unsigned char* __restrict__ S,
                      const float* __restrict__ logC,
                      float* __restrict__ rowv) {
  const int tid  = threadIdx.x;
  const int lane = tid & 63;
  const int wid  = tid >> 6;
  const int row  = blockIdx.x * 4 + wid;      // 4096 blocks -> BH rows
  const size_t plane = (size_t)BH * KC;
  const unsigned char* Sr = S + (size_t)row * KC + lane * 16;
  const int kb = lane * 16;

  uint4 vz1 = *reinterpret_cast<const uint4*>(Sr + 0 * plane);
  uint4 vz2 = *reinterpret_cast<const uint4*>(Sr + 1 * plane);
  uint4 vp1 = *reinterpret_cast<const uint4*>(Sr + 2 * plane);
  uint4 vp2 = *reinterpret_cast<const uint4*>(Sr + 3 * plane);

  float dp1 = 0.f, dp2 = 0.f, dz1 = 0.f, dz2 = 0.f, nz1 = 0.f, nz2 = 0.f;
  float tv[16];

  {
    const unsigned w1[4] = {vp1.x, vp1.y, vp1.z, vp1.w};
    const unsigned w2[4] = {vp2.x, vp2.y, vp2.z, vp2.w};
    float lc1[16], lc2[16];
    #pragma unroll
    for (int q = 0; q < 4; ++q) {
      *reinterpret_cast<float4*>(&lc1[q * 4]) =
          *reinterpret_cast<const float4*>(logC + 2 * KC + kb + q * 4);
      *reinterpret_cast<float4*>(&lc2[q * 4]) =
          *reinterpret_cast<const float4*>(logC + 3 * KC + kb + q * 4);
    }
    #pragma unroll
    for (int e = 0; e < 16; ++e) {
      unsigned b1 = (w1[e >> 2] >> ((e & 3) * 8)) & 0xffu;
      unsigned b2 = (w2[e >> 2] >> ((e & 3) * 8)) & 0xffu;
      float g1 = decG(b1, lc1[e]);
      float g2 = decG(b2, lc2[e]);
      dp1 += __expf(g1);
      dp2 += __expf(g2);
      tv[e] = g1 + g2;
    }
  }
  {
    const unsigned w1[4] = {vz1.x, vz1.y, vz1.z, vz1.w};
    const unsigned w2[4] = {vz2.x, vz2.y, vz2.z, vz2.w};
    float lc1[16], lc2[16];
    #pragma unroll
    for (int q = 0; q < 4; ++q) {
      *reinterpret_cast<float4*>(&lc1[q * 4]) =
          *reinterpret_cast<const float4*>(logC + 0 * KC + kb + q * 4);
      *reinterpret_cast<float4*>(&lc2[q * 4]) =
          *reinterpret_cast<const float4*>(logC + 1 * KC + kb + q * 4);
    }
    #pragma unroll
    for (int e = 0; e < 16; ++e) {
      unsigned b1 = (w1[e >> 2] >> ((e & 3) * 8)) & 0xffu;
      unsigned b2 = (w2[e >> 2] >> ((e & 3) * 8)) & 0xffu;
      float e1 = __expf(decG(b1, lc1[e]));
      float e2 = __expf(decG(b2, lc2[e]));
      dz1 += e1; nz1 += e1 * tv[e];
      dz2 += e2; nz2 += e2 * tv[e];
    }
  }

  #pragma unroll
  for (int m = 1; m < 64; m <<= 1) {
    dp1 += __shfl_xor(dp1, m); dp2 += __shfl_xor(dp2, m);
    dz1 += __shfl_xor(dz1, m); dz2 += __shfl_xor(dz2, m);
    nz1 += __shfl_xor(nz1, m); nz2 += __shfl_xor(nz2, m);
  }

  __shared__ float red[4];
  if (lane == 0)
    red[wid] = nz1 / dz1 + nz2 / dz2 - 2.0f * (__logf(dp1) + __logf(dp2));
  __syncthreads();
  if (tid == 0)
    rowv[blockIdx.x] = red[0] + red[1] + red[2] + red[3];
}

// 4096 partials -> 16 blocks -> 16 atomics
__global__ void fin_reduce_kernel(const float* __restrict__ rowv,
                                  float* __restrict__ out) {
  int i = blockIdx.x * 256 + threadIdx.x;
  float v = rowv[i];
  #pragma unroll
  for (int m = 1; m < 64; m <<= 1) v += __shfl_xor(v, m);
  __shared__ float ws[4];
  int lane = threadIdx.x & 63, wid = threadIdx.x >> 6;
  if (lane == 0) ws[wid] = v;
  __syncthreads();
  if (threadIdx.x == 0)
    atomicAdd(out, (ws[0] + ws[1] + ws[2] + ws[3]) * (-1.0f / 65536.0f));
}

extern "C" void kernel_launch(void* const* d_in, const int* in_sizes, int n_in,
                              void* d_out, int out_size, void* d_ws, size_t ws_size,
                              hipStream_t stream) {
  const float* z = (const float*)d_in[0];
  const float* p = (const float*)d_in[1];
  const float* c = (const float*)d_in[2];
  char* ws = (char*)d_ws;
  // layout: XA bf16 33.55MB | Cn 0.5MB | colsum 16KB | logC 16KB |
  //         rowv 16KB | S u8 67.1MB
  unsigned short* Xn = (unsigned short*)(ws);
  unsigned short* Cn = (unsigned short*)(ws + 33554432);
  float* colsum = (float*)(ws + 34078720);
  float* logC   = (float*)(ws + 34095104);
  float* rowv   = (float*)(ws + 34111488);
  unsigned char* S = (unsigned char*)(ws + 34127872);
  float* out = (float*)d_out;

  norm_rows_kernel<<<16640, 256, 0, stream>>>(z, p, c, Xn, Cn, colsum, out);
  gemm_s_kernel<<<1024, 256, 0, stream>>>(Xn, Cn, colsum, S);
  fin_logC_kernel<<<16, 256, 0, stream>>>(colsum, logC);
  pass2_mem_kernel<<<4096, 256, 0, stream>>>(S, logC, rowv);
  fin_reduce_kernel<<<16, 256, 0, stream>>>(rowv, out);
}

// Round 16
// 111.397 us; speedup vs baseline: 1.2560x; 1.2560x over previous
//
#include <hip/hip_runtime.h>
#include <math.h>

#define BH  16384   // half batch
#define B2  32768
#define DIM 256
#define KC  1024    // clusters

typedef __bf16 bf16x8 __attribute__((ext_vector_type(8)));
typedef float  f32x4  __attribute__((ext_vector_type(4)));

__device__ __forceinline__ unsigned short f2bf(float f) {
  unsigned int u = __float_as_uint(f);
  u += 0x7FFFu + ((u >> 16) & 1u);   // RNE; inputs are finite
  return (unsigned short)(u >> 16);
}

__device__ __forceinline__ float vsqrt(float x) {
  float r; asm("v_sqrt_f32 %0, %1" : "=v"(r) : "v"(x)); return r;
}

__device__ __forceinline__ void gld_lds16(const void* g, void* l) {
  __builtin_amdgcn_global_load_lds(
      (const __attribute__((address_space(1))) void*)g,
      (__attribute__((address_space(3))) void*)l, 16, 0, 0);
}

// one wave per row: l2-normalize and convert to bf16.
// Blocks 0..15 also zero colsum; block 16 zeros out.
__global__ void norm_rows_kernel(const float* __restrict__ z,
                                 const float* __restrict__ p,
                                 const float* __restrict__ c,
                                 unsigned short* __restrict__ Xn,
                                 unsigned short* __restrict__ Cn,
                                 float* __restrict__ colsum,
                                 float* __restrict__ out) {
  if (blockIdx.x < 16) colsum[blockIdx.x * 256 + threadIdx.x] = 0.0f;
  if (blockIdx.x == 16 && threadIdx.x == 0) out[0] = 0.0f;

  int wave = threadIdx.x >> 6;
  int lane = threadIdx.x & 63;
  int row  = blockIdx.x * 4 + wave;          // 0 .. 66559
  const float* src; unsigned short* dst; int r;
  if (row < B2)        { src = z; dst = Xn; r = row; }
  else if (row < 2*B2) { src = p; dst = Xn + (size_t)B2 * DIM; r = row - B2; }
  else                 { src = c; dst = Cn; r = row - 2*B2; }
  float4 v = *reinterpret_cast<const float4*>(src + (size_t)r * DIM + lane * 4);
  float ss = v.x*v.x + v.y*v.y + v.z*v.z + v.w*v.w;
  #pragma unroll
  for (int m = 1; m < 64; m <<= 1) ss += __shfl_xor(ss, m);
  float inv = 1.0f / fmaxf(vsqrt(ss), 1e-12f);
  ushort4 o;
  o.x = f2bf(v.x * inv); o.y = f2bf(v.y * inv);
  o.z = f2bf(v.z * inv); o.w = f2bf(v.w * inv);
  *reinterpret_cast<ushort4*>(dst + (size_t)r * DIM + lane * 4) = o;
}

__global__ void fin_logC_kernel(const float* __restrict__ colsum,
                                float* __restrict__ logC) {
  int i = blockIdx.x * 256 + threadIdx.x;
  if (i < 4 * KC) logC[i] = 40.0f + __logf(colsum[i]);
}

// gemm_s: S[mat][b][k] = u8 quantized dot; colsum[mat][k] += LUT[e]
// r9/r14-EXACT structure (BK=64, 256 thr, (256,2), __syncthreads dbuf,
// B staged in LDS, VGPR ~120, no spill). 6x-replicated lesson: every
// variant adding register pressure (big tiles, 512-thr, (256,4)) or
// scheduler fences (sched_barrier/asm vmcnt) or mixing B-global loads
// into the vmcnt queue regresses 1.5-3x. This shape is the toolchain
// optimum for this loop; do not touch.
__global__ __launch_bounds__(256, 2)
void gemm_s_kernel(const unsigned short* __restrict__ XA,  // [4][BH][DIM]
                   const unsigned short* __restrict__ Cn,  // [KC][DIM]
                   float* __restrict__ colsum,
                   unsigned char* __restrict__ S) {        // [4][BH][KC] u8
  __shared__ __align__(16) char lds[65536 + 4096];  // tiles + 256x4 f32 LUT
  float* lut4 = (float*)(lds + 65536);
  const int id  = blockIdx.x;            // 1024
  const int xcd = id & 7, idx = id >> 3;
  const int wk  = xcd * 128 + idx;       // bijective (1024 % 8 == 0)
  const int panel = wk >> 3, col = wk & 7;
  const int tm0 = panel * 128, tn0 = col * 128;

  const int tid  = threadIdx.x;
  const int lane = tid & 63;
  const int wid  = tid >> 6;
  const int wm   = wid >> 1, wn = wid & 1;
  const int l15  = lane & 15, l4 = lane >> 4;
  const int slot = tid & 3;

  int arow[4], acs[4];
  #pragma unroll
  for (int it = 0; it < 4; ++it) {
    int sl = it * 256 + tid;
    int r = sl >> 3, c = sl & 7;
    arow[it] = r;
    acs[it]  = c ^ (r & 7);    // pre-swizzled source chunk (involution)
  }
  const char* Abase = (const char*)XA + (size_t)tm0 * 512;
  const char* Bbase = (const char*)Cn + (size_t)tn0 * 512;

  auto stage = [&](int t) {
    const int mat = t >> 2;
    const int bk  = t & 3;
    const int b   = t & 1;
    const char* ab = Abase + ((size_t)mat << 23);   // mat * BH * 512
    #pragma unroll
    for (int it = 0; it < 4; ++it) {
      gld_lds16(ab + (size_t)arow[it] * 512 + bk * 128 + acs[it] * 16,
                lds + b * 16384 + (it * 256 + tid) * 16);
      gld_lds16(Bbase + (size_t)arow[it] * 512 + bk * 128 + acs[it] * 16,
                lds + 32768 + b * 16384 + (it * 256 + tid) * 16);
    }
  };

  // build LUT (before the barrier that precedes first compute)
  if (tid < 256) {
    float d = ((float)tid - 127.5f) * (1.0f / 255.0f);
    float L = 20.0f * vsqrt(2.0f - 2.0f * d);
    float v = __expf(L - 40.0f);
    ((float4*)lut4)[tid] = (float4){v, v, v, v};
  }

  f32x4 acc[4][4];
  stage(0);
  __syncthreads();

  for (int t = 0; t < 16; ++t) {
    if (t < 15) stage(t + 1);
    const int b  = t & 1;
    const int mat = t >> 2, bk = t & 3;

    if (bk == 0) {
      #pragma unroll
      for (int fi = 0; fi < 4; ++fi)
        #pragma unroll
        for (int fj = 0; fj < 4; ++fj)
          acc[fi][fj] = (f32x4){0.f, 0.f, 0.f, 0.f};
    }

    #pragma unroll
    for (int kc = 0; kc < 2; ++kc) {
      bf16x8 aF[4], bF[4];
      #pragma unroll
      for (int f = 0; f < 4; ++f) {
        const int ra = wm * 64 + f * 16 + l15;
        aF[f] = *reinterpret_cast<const bf16x8*>(
            lds + b * 16384 + ra * 128 + ((((kc << 2) | l4) ^ (ra & 7)) << 4));
        const int rb = wn * 64 + f * 16 + l15;
        bF[f] = *reinterpret_cast<const bf16x8*>(
            lds + 32768 + b * 16384 + rb * 128 + ((((kc << 2) | l4) ^ (rb & 7)) << 4));
      }
      #pragma unroll
      for (int fi = 0; fi < 4; ++fi)
        #pragma unroll
        for (int fj = 0; fj < 4; ++fj)
          acc[fi][fj] = __builtin_amdgcn_mfma_f32_16x16x32_bf16(
              aF[fi], bF[fj], acc[fi][fj], 0, 0, 0);
    }

    if (bk == 3) {
      unsigned char* Sp = S + ((size_t)mat * BH + tm0) * KC + tn0;
      #pragma unroll
      for (int fj = 0; fj < 4; ++fj) {
        float cp = 0.0f;
        #pragma unroll
        for (int fi = 0; fi < 4; ++fi)
          #pragma unroll
          for (int i = 0; i < 4; ++i) {
            float v = fmaf(acc[fi][fj][i], 255.0f, 128.0f);
            v = fminf(fmaxf(v, 0.0f), 255.0f);
            unsigned e = (unsigned)v;
            cp += lut4[(e << 2) | slot];
            int row  = wm * 64 + fi * 16 + l4 * 4 + i;
            int ccol = wn * 64 + fj * 16 + l15;
            Sp[(size_t)row * KC + ccol] = (unsigned char)e;
          }
        cp += __shfl_xor(cp, 16);
        cp += __shfl_xor(cp, 32);
        if (l4 == 0)
          atomicAdd(&colsum[mat * KC + tn0 + wn * 64 + fj * 16 + l15], cp);
      }
    }
    __syncthreads();
  }
}

// one wave per row: 4 uint4 loads cover the full row in all 4 planes.
// L(d_e) via 256-entry 4-replica LDS LUT (kills the per-element cvt+fma+
// sqrt chain: 1 ds_read + sub + exp per element).
__global__ __launch_bounds__(256)
void pass2_mem_kernel(const unsigned char* __restrict__ S,
                      const float* __restrict__ logC,
                      float* __restrict__ rowv) {
  __shared__ float llut[1024];   // 256 entries x 4 replicas
  const int tid  = threadIdx.x;
  const int lane = tid & 63;
  const int wid  = tid >> 6;
  const int slot = lane & 3;
  const int row  = blockIdx.x * 4 + wid;      // 4096 blocks -> BH rows
  const size_t plane = (size_t)BH * KC;
  const unsigned char* Sr = S + (size_t)row * KC + lane * 16;
  const int kb = lane * 16;

  {
    float d = ((float)tid - 127.5f) * (1.0f / 255.0f);
    float L = 20.0f * vsqrt(2.0f - 2.0f * d);
    ((float4*)llut)[tid] = (float4){L, L, L, L};
  }

  uint4 vz1 = *reinterpret_cast<const uint4*>(Sr + 0 * plane);
  uint4 vz2 = *reinterpret_cast<const uint4*>(Sr + 1 * plane);
  uint4 vp1 = *reinterpret_cast<const uint4*>(Sr + 2 * plane);
  uint4 vp2 = *reinterpret_cast<const uint4*>(Sr + 3 * plane);
  __syncthreads();   // publish LUT

  float dp1 = 0.f, dp2 = 0.f, dz1 = 0.f, dz2 = 0.f, nz1 = 0.f, nz2 = 0.f;
  float tv[16];

  {
    const unsigned w1[4] = {vp1.x, vp1.y, vp1.z, vp1.w};
    const unsigned w2[4] = {vp2.x, vp2.y, vp2.z, vp2.w};
    float lc1[16], lc2[16];
    #pragma unroll
    for (int q = 0; q < 4; ++q) {
      *reinterpret_cast<float4*>(&lc1[q * 4]) =
          *reinterpret_cast<const float4*>(logC + 2 * KC + kb + q * 4);
      *reinterpret_cast<float4*>(&lc2[q * 4]) =
          *reinterpret_cast<const float4*>(logC + 3 * KC + kb + q * 4);
    }
    #pragma unroll
    for (int e = 0; e < 16; ++e) {
      unsigned b1 = (w1[e >> 2] >> ((e & 3) * 8)) & 0xffu;
      unsigned b2 = (w2[e >> 2] >> ((e & 3) * 8)) & 0xffu;
      float g1 = llut[(b1 << 2) | slot] - lc1[e];
      float g2 = llut[(b2 << 2) | slot] - lc2[e];
      dp1 += __expf(g1);
      dp2 += __expf(g2);
      tv[e] = g1 + g2;
    }
  }
  {
    const unsigned w1[4] = {vz1.x, vz1.y, vz1.z, vz1.w};
    const unsigned w2[4] = {vz2.x, vz2.y, vz2.z, vz2.w};
    float lc1[16], lc2[16];
    #pragma unroll
    for (int q = 0; q < 4; ++q) {
      *reinterpret_cast<float4*>(&lc1[q * 4]) =
          *reinterpret_cast<const float4*>(logC + 0 * KC + kb + q * 4);
      *reinterpret_cast<float4*>(&lc2[q * 4]) =
          *reinterpret_cast<const float4*>(logC + 1 * KC + kb + q * 4);
    }
    #pragma unroll
    for (int e = 0; e < 16; ++e) {
      unsigned b1 = (w1[e >> 2] >> ((e & 3) * 8)) & 0xffu;
      unsigned b2 = (w2[e >> 2] >> ((e & 3) * 8)) & 0xffu;
      float e1 = __expf(llut[(b1 << 2) | slot] - lc1[e]);
      float e2 = __expf(llut[(b2 << 2) | slot] - lc2[e]);
      dz1 += e1; nz1 += e1 * tv[e];
      dz2 += e2; nz2 += e2 * tv[e];
    }
  }

  #pragma unroll
  for (int m = 1; m < 64; m <<= 1) {
    dp1 += __shfl_xor(dp1, m); dp2 += __shfl_xor(dp2, m);
    dz1 += __shfl_xor(dz1, m); dz2 += __shfl_xor(dz2, m);
    nz1 += __shfl_xor(nz1, m); nz2 += __shfl_xor(nz2, m);
  }

  __shared__ float red[4];
  if (lane == 0)
    red[wid] = nz1 / dz1 + nz2 / dz2 - 2.0f * __logf(dp1 * dp2);
  __syncthreads();
  if (tid == 0)
    rowv[blockIdx.x] = red[0] + red[1] + red[2] + red[3];
}

// 4096 partials -> 16 blocks -> 16 atomics
__global__ void fin_reduce_kernel(const float* __restrict__ rowv,
                                  float* __restrict__ out) {
  int i = blockIdx.x * 256 + threadIdx.x;
  float v = rowv[i];
  #pragma unroll
  for (int m = 1; m < 64; m <<= 1) v += __shfl_xor(v, m);
  __shared__ float ws[4];
  int lane = threadIdx.x & 63, wid = threadIdx.x >> 6;
  if (lane == 0) ws[wid] = v;
  __syncthreads();
  if (threadIdx.x == 0)
    atomicAdd(out, (ws[0] + ws[1] + ws[2] + ws[3]) * (-1.0f / 65536.0f));
}

extern "C" void kernel_launch(void* const* d_in, const int* in_sizes, int n_in,
                              void* d_out, int out_size, void* d_ws, size_t ws_size,
                              hipStream_t stream) {
  const float* z = (const float*)d_in[0];
  const float* p = (const float*)d_in[1];
  const float* c = (const float*)d_in[2];
  char* ws = (char*)d_ws;
  // layout: XA bf16 33.55MB | Cn 0.5MB | colsum 16KB | logC 16KB |
  //         rowv 16KB | S u8 67.1MB
  unsigned short* Xn = (unsigned short*)(ws);
  unsigned short* Cn = (unsigned short*)(ws + 33554432);
  float* colsum = (float*)(ws + 34078720);
  float* logC   = (float*)(ws + 34095104);
  float* rowv   = (float*)(ws + 34111488);
  unsigned char* S = (unsigned char*)(ws + 34127872);
  float* out = (float*)d_out;

  norm_rows_kernel<<<16640, 256, 0, stream>>>(z, p, c, Xn, Cn, colsum, out);
  gemm_s_kernel<<<1024, 256, 0, stream>>>(Xn, Cn, colsum, S);
  fin_logC_kernel<<<16, 256, 0, stream>>>(colsum, logC);
  pass2_mem_kernel<<<4096, 256, 0, stream>>>(S, logC, rowv);
  fin_reduce_kernel<<<16, 256, 0, stream>>>(rowv, out);
}

// Round 17
// 108.812 us; speedup vs baseline: 1.2858x; 1.0238x over previous
//
#include <hip/hip_runtime.h>
#include <math.h>

#define BH  16384   // half batch
#define B2  32768
#define DIM 256
#define KC  1024    // clusters

typedef __bf16 bf16x8 __attribute__((ext_vector_type(8)));
typedef float  f32x4  __attribute__((ext_vector_type(4)));

__device__ __forceinline__ unsigned short f2bf(float f) {
  unsigned int u = __float_as_uint(f);
  u += 0x7FFFu + ((u >> 16) & 1u);   // RNE; inputs are finite
  return (unsigned short)(u >> 16);
}

__device__ __forceinline__ float vsqrt(float x) {
  float r; asm("v_sqrt_f32 %0, %1" : "=v"(r) : "v"(x)); return r;
}

__device__ __forceinline__ void gld_lds16(const void* g, void* l) {
  __builtin_amdgcn_global_load_lds(
      (const __attribute__((address_space(1))) void*)g,
      (__attribute__((address_space(3))) void*)l, 16, 0, 0);
}

// one wave per row: l2-normalize and convert to bf16.
// Blocks 0..15 also zero colsum; block 16 zeros out.
__global__ void norm_rows_kernel(const float* __restrict__ z,
                                 const float* __restrict__ p,
                                 const float* __restrict__ c,
                                 unsigned short* __restrict__ Xn,
                                 unsigned short* __restrict__ Cn,
                                 float* __restrict__ colsum,
                                 float* __restrict__ out) {
  if (blockIdx.x < 16) colsum[blockIdx.x * 256 + threadIdx.x] = 0.0f;
  if (blockIdx.x == 16 && threadIdx.x == 0) out[0] = 0.0f;

  int wave = threadIdx.x >> 6;
  int lane = threadIdx.x & 63;
  int row  = blockIdx.x * 4 + wave;          // 0 .. 66559
  const float* src; unsigned short* dst; int r;
  if (row < B2)        { src = z; dst = Xn; r = row; }
  else if (row < 2*B2) { src = p; dst = Xn + (size_t)B2 * DIM; r = row - B2; }
  else                 { src = c; dst = Cn; r = row - 2*B2; }
  float4 v = *reinterpret_cast<const float4*>(src + (size_t)r * DIM + lane * 4);
  float ss = v.x*v.x + v.y*v.y + v.z*v.z + v.w*v.w;
  #pragma unroll
  for (int m = 1; m < 64; m <<= 1) ss += __shfl_xor(ss, m);
  float inv = 1.0f / fmaxf(vsqrt(ss), 1e-12f);
  ushort4 o;
  o.x = f2bf(v.x * inv); o.y = f2bf(v.y * inv);
  o.z = f2bf(v.z * inv); o.w = f2bf(v.w * inv);
  *reinterpret_cast<ushort4*>(dst + (size_t)r * DIM + lane * 4) = o;
}

__global__ void fin_logC_kernel(const float* __restrict__ colsum,
                                float* __restrict__ logC) {
  int i = blockIdx.x * 256 + threadIdx.x;
  if (i < 4 * KC) logC[i] = 40.0f + __logf(colsum[i]);
}

// gemm_s: S[mat][b][k] = u8 quantized dot; colsum[mat][k] += LUT[e]
// r9/r14-EXACT structure (BK=64, 256 thr, (256,2), __syncthreads dbuf,
// B staged in LDS, VGPR ~120, no spill). 6x-replicated lesson: every
// variant adding register pressure (big tiles, 512-thr, (256,4)) or
// scheduler fences (sched_barrier/asm vmcnt) or mixing B-global loads
// into the vmcnt queue regresses 1.5-3x. This shape is the toolchain
// optimum for this loop; do not touch.
__global__ __launch_bounds__(256, 2)
void gemm_s_kernel(const unsigned short* __restrict__ XA,  // [4][BH][DIM]
                   const unsigned short* __restrict__ Cn,  // [KC][DIM]
                   float* __restrict__ colsum,
                   unsigned char* __restrict__ S) {        // [4][BH][KC] u8
  __shared__ __align__(16) char lds[65536 + 4096];  // tiles + 256x4 f32 LUT
  float* lut4 = (float*)(lds + 65536);
  const int id  = blockIdx.x;            // 1024
  const int xcd = id & 7, idx = id >> 3;
  const int wk  = xcd * 128 + idx;       // bijective (1024 % 8 == 0)
  const int panel = wk >> 3, col = wk & 7;
  const int tm0 = panel * 128, tn0 = col * 128;

  const int tid  = threadIdx.x;
  const int lane = tid & 63;
  const int wid  = tid >> 6;
  const int wm   = wid >> 1, wn = wid & 1;
  const int l15  = lane & 15, l4 = lane >> 4;
  const int slot = tid & 3;

  int arow[4], acs[4];
  #pragma unroll
  for (int it = 0; it < 4; ++it) {
    int sl = it * 256 + tid;
    int r = sl >> 3, c = sl & 7;
    arow[it] = r;
    acs[it]  = c ^ (r & 7);    // pre-swizzled source chunk (involution)
  }
  const char* Abase = (const char*)XA + (size_t)tm0 * 512;
  const char* Bbase = (const char*)Cn + (size_t)tn0 * 512;

  auto stage = [&](int t) {
    const int mat = t >> 2;
    const int bk  = t & 3;
    const int b   = t & 1;
    const char* ab = Abase + ((size_t)mat << 23);   // mat * BH * 512
    #pragma unroll
    for (int it = 0; it < 4; ++it) {
      gld_lds16(ab + (size_t)arow[it] * 512 + bk * 128 + acs[it] * 16,
                lds + b * 16384 + (it * 256 + tid) * 16);
      gld_lds16(Bbase + (size_t)arow[it] * 512 + bk * 128 + acs[it] * 16,
                lds + 32768 + b * 16384 + (it * 256 + tid) * 16);
    }
  };

  // build LUT (before the barrier that precedes first compute)
  if (tid < 256) {
    float d = ((float)tid - 127.5f) * (1.0f / 255.0f);
    float L = 20.0f * vsqrt(2.0f - 2.0f * d);
    float v = __expf(L - 40.0f);
    ((float4*)lut4)[tid] = (float4){v, v, v, v};
  }

  f32x4 acc[4][4];
  stage(0);
  __syncthreads();

  for (int t = 0; t < 16; ++t) {
    if (t < 15) stage(t + 1);
    const int b  = t & 1;
    const int mat = t >> 2, bk = t & 3;

    if (bk == 0) {
      #pragma unroll
      for (int fi = 0; fi < 4; ++fi)
        #pragma unroll
        for (int fj = 0; fj < 4; ++fj)
          acc[fi][fj] = (f32x4){0.f, 0.f, 0.f, 0.f};
    }

    #pragma unroll
    for (int kc = 0; kc < 2; ++kc) {
      bf16x8 aF[4], bF[4];
      #pragma unroll
      for (int f = 0; f < 4; ++f) {
        const int ra = wm * 64 + f * 16 + l15;
        aF[f] = *reinterpret_cast<const bf16x8*>(
            lds + b * 16384 + ra * 128 + ((((kc << 2) | l4) ^ (ra & 7)) << 4));
        const int rb = wn * 64 + f * 16 + l15;
        bF[f] = *reinterpret_cast<const bf16x8*>(
            lds + 32768 + b * 16384 + rb * 128 + ((((kc << 2) | l4) ^ (rb & 7)) << 4));
      }
      #pragma unroll
      for (int fi = 0; fi < 4; ++fi)
        #pragma unroll
        for (int fj = 0; fj < 4; ++fj)
          acc[fi][fj] = __builtin_amdgcn_mfma_f32_16x16x32_bf16(
              aF[fi], bF[fj], acc[fi][fj], 0, 0, 0);
    }

    if (bk == 3) {
      unsigned char* Sp = S + ((size_t)mat * BH + tm0) * KC + tn0;
      #pragma unroll
      for (int fj = 0; fj < 4; ++fj) {
        float cp = 0.0f;
        #pragma unroll
        for (int fi = 0; fi < 4; ++fi)
          #pragma unroll
          for (int i = 0; i < 4; ++i) {
            float v = fmaf(acc[fi][fj][i], 255.0f, 128.0f);
            v = fminf(fmaxf(v, 0.0f), 255.0f);
            unsigned e = (unsigned)v;
            cp += lut4[(e << 2) | slot];
            int row  = wm * 64 + fi * 16 + l4 * 4 + i;
            int ccol = wn * 64 + fj * 16 + l15;
            Sp[(size_t)row * KC + ccol] = (unsigned char)e;
          }
        cp += __shfl_xor(cp, 16);
        cp += __shfl_xor(cp, 32);
        if (l4 == 0)
          atomicAdd(&colsum[mat * KC + tn0 + wn * 64 + fj * 16 + l15], cp);
      }
    }
    __syncthreads();
  }
}

// decode u8 -> G = L(d_e) - lc  (independent 5-op VALU chain; r16 showed
// this beats an LDS LUT here: pass2 is stream-bound, the ALU hides free,
// while LUT gathers add serialized LDS latency + a barrier)
__device__ __forceinline__ float decG(unsigned e, float lc) {
  float d = fmaf((float)e, 1.0f / 255.0f, -0.5f);
  float L = 20.0f * vsqrt(fmaf(-2.0f, d, 2.0f));
  return L - lc;
}

// one wave per row: 4 uint4 loads cover the full row in all 4 planes.
__global__ __launch_bounds__(256)
void pass2_mem_kernel(const unsigned char* __restrict__ S,
                      const float* __restrict__ logC,
                      float* __restrict__ rowv) {
  const int tid  = threadIdx.x;
  const int lane = tid & 63;
  const int wid  = tid >> 6;
  const int row  = blockIdx.x * 4 + wid;      // 4096 blocks -> BH rows
  const size_t plane = (size_t)BH * KC;
  const unsigned char* Sr = S + (size_t)row * KC + lane * 16;
  const int kb = lane * 16;

  uint4 vz1 = *reinterpret_cast<const uint4*>(Sr + 0 * plane);
  uint4 vz2 = *reinterpret_cast<const uint4*>(Sr + 1 * plane);
  uint4 vp1 = *reinterpret_cast<const uint4*>(Sr + 2 * plane);
  uint4 vp2 = *reinterpret_cast<const uint4*>(Sr + 3 * plane);

  float dp1 = 0.f, dp2 = 0.f, dz1 = 0.f, dz2 = 0.f, nz1 = 0.f, nz2 = 0.f;
  float tv[16];

  {
    const unsigned w1[4] = {vp1.x, vp1.y, vp1.z, vp1.w};
    const unsigned w2[4] = {vp2.x, vp2.y, vp2.z, vp2.w};
    float lc1[16], lc2[16];
    #pragma unroll
    for (int q = 0; q < 4; ++q) {
      *reinterpret_cast<float4*>(&lc1[q * 4]) =
          *reinterpret_cast<const float4*>(logC + 2 * KC + kb + q * 4);
      *reinterpret_cast<float4*>(&lc2[q * 4]) =
          *reinterpret_cast<const float4*>(logC + 3 * KC + kb + q * 4);
    }
    #pragma unroll
    for (int e = 0; e < 16; ++e) {
      unsigned b1 = (w1[e >> 2] >> ((e & 3) * 8)) & 0xffu;
      unsigned b2 = (w2[e >> 2] >> ((e & 3) * 8)) & 0xffu;
      float g1 = decG(b1, lc1[e]);
      float g2 = decG(b2, lc2[e]);
      dp1 += __expf(g1);
      dp2 += __expf(g2);
      tv[e] = g1 + g2;
    }
  }
  {
    const unsigned w1[4] = {vz1.x, vz1.y, vz1.z, vz1.w};
    const unsigned w2[4] = {vz2.x, vz2.y, vz2.z, vz2.w};
    float lc1[16], lc2[16];
    #pragma unroll
    for (int q = 0; q < 4; ++q) {
      *reinterpret_cast<float4*>(&lc1[q * 4]) =
          *reinterpret_cast<const float4*>(logC + 0 * KC + kb + q * 4);
      *reinterpret_cast<float4*>(&lc2[q * 4]) =
          *reinterpret_cast<const float4*>(logC + 1 * KC + kb + q * 4);
    }
    #pragma unroll
    for (int e = 0; e < 16; ++e) {
      unsigned b1 = (w1[e >> 2] >> ((e & 3) * 8)) & 0xffu;
      unsigned b2 = (w2[e >> 2] >> ((e & 3) * 8)) & 0xffu;
      float e1 = __expf(decG(b1, lc1[e]));
      float e2 = __expf(decG(b2, lc2[e]));
      dz1 += e1; nz1 += e1 * tv[e];
      dz2 += e2; nz2 += e2 * tv[e];
    }
  }

  #pragma unroll
  for (int m = 1; m < 64; m <<= 1) {
    dp1 += __shfl_xor(dp1, m); dp2 += __shfl_xor(dp2, m);
    dz1 += __shfl_xor(dz1, m); dz2 += __shfl_xor(dz2, m);
    nz1 += __shfl_xor(nz1, m); nz2 += __shfl_xor(nz2, m);
  }

  __shared__ float red[4];
  if (lane == 0)
    red[wid] = nz1 / dz1 + nz2 / dz2 - 2.0f * __logf(dp1 * dp2);
  __syncthreads();
  if (tid == 0)
    rowv[blockIdx.x] = red[0] + red[1] + red[2] + red[3];
}

// 4096 partials -> 16 blocks -> 16 atomics
__global__ void fin_reduce_kernel(const float* __restrict__ rowv,
                                  float* __restrict__ out) {
  int i = blockIdx.x * 256 + threadIdx.x;
  float v = rowv[i];
  #pragma unroll
  for (int m = 1; m < 64; m <<= 1) v += __shfl_xor(v, m);
  __shared__ float ws[4];
  int lane = threadIdx.x & 63, wid = threadIdx.x >> 6;
  if (lane == 0) ws[wid] = v;
  __syncthreads();
  if (threadIdx.x == 0)
    atomicAdd(out, (ws[0] + ws[1] + ws[2] + ws[3]) * (-1.0f / 65536.0f));
}

extern "C" void kernel_launch(void* const* d_in, const int* in_sizes, int n_in,
                              void* d_out, int out_size, void* d_ws, size_t ws_size,
                              hipStream_t stream) {
  const float* z = (const float*)d_in[0];
  const float* p = (const float*)d_in[1];
  const float* c = (const float*)d_in[2];
  char* ws = (char*)d_ws;
  // layout: XA bf16 33.55MB | Cn 0.5MB | colsum 16KB | logC 16KB |
  //         rowv 16KB | S u8 67.1MB
  unsigned short* Xn = (unsigned short*)(ws);
  unsigned short* Cn = (unsigned short*)(ws + 33554432);
  float* colsum = (float*)(ws + 34078720);
  float* logC   = (float*)(ws + 34095104);
  float* rowv   = (float*)(ws + 34111488);
  unsigned char* S = (unsigned char*)(ws + 34127872);
  float* out = (float*)d_out;

  norm_rows_kernel<<<16640, 256, 0, stream>>>(z, p, c, Xn, Cn, colsum, out);
  gemm_s_kernel<<<1024, 256, 0, stream>>>(Xn, Cn, colsum, S);
  fin_logC_kernel<<<16, 256, 0, stream>>>(colsum, logC);
  pass2_mem_kernel<<<4096, 256, 0, stream>>>(S, logC, rowv);
  fin_reduce_kernel<<<16, 256, 0, stream>>>(rowv, out);
}